// Round 3
// baseline (239.975 us; speedup 1.0000x reference)
//
#include <hip/hip_runtime.h>

#define DI __device__ __forceinline__

typedef __bf16 bf8 __attribute__((ext_vector_type(8)));
typedef float f4 __attribute__((ext_vector_type(4)));
typedef unsigned short us4 __attribute__((ext_vector_type(4)));
typedef unsigned short us8 __attribute__((ext_vector_type(8)));

// dims
#define BB 8
#define NN 4096
#define DD 512
#define RED 128
#define GG 32
#define HID 129

DI float b2f(unsigned short u) {
    union { unsigned int i; float f; } c; c.i = ((unsigned int)u) << 16; return c.f;
}
DI unsigned short f2b(float f) {
    union { float f; unsigned int i; } c; c.f = f;
    unsigned int u = c.i;
    return (unsigned short)((u + 0x7fffu + ((u >> 16) & 1u)) >> 16);
}

typedef const __attribute__((address_space(1))) void* gp1_t;
typedef __attribute__((address_space(3))) void* lp3_t;
// async global->LDS DMA, 16B per lane; lds base must be wave-uniform, HW adds lane*16
DI void gld16(const void* g, void* l) {
    __builtin_amdgcn_global_load_lds((gp1_t)g, (lp3_t)l, 16, 0, 0);
}

// ---------------- kernel 1: x -> bf16 + pooled partial sums (fully block-reduced), kcvt merged ----------------
__global__ __launch_bounds__(256) void kpre(const float* __restrict__ x,
                                            const float* __restrict__ conv1_w,
                                            const float* __restrict__ conv2_w,
                                            float* __restrict__ part,
                                            unsigned short* __restrict__ xb,
                                            unsigned short* __restrict__ c1b,
                                            unsigned short* __restrict__ c2b) {
    int c = blockIdx.x, b = blockIdx.y, t = threadIdx.x;
    __shared__ float red[2][512];
    if (c >= 128) {
        int idx = ((c - 128) * 8 + b) * 256 + t;    // 0..18431, need 17408
        if (idx < 16384) {
            size_t off = (size_t)idx * 4;
            float4 v = *(const float4*)(conv1_w + off);
            us4 o; o[0] = f2b(v.x); o[1] = f2b(v.y); o[2] = f2b(v.z); o[3] = f2b(v.w);
            *(us4*)(c1b + off) = o;
        } else if (idx < 17408) {
            size_t off = (size_t)(idx - 16384) * 4;
            float4 v = *(const float4*)(conv2_w + off);
            us4 o; o[0] = f2b(v.x); o[1] = f2b(v.y); o[2] = f2b(v.z); o[3] = f2b(v.w);
            *(us4*)(c2b + off) = o;
        }
        return;
    }
    int rg = t >> 7, cg = t & 127;
    int row0 = c * 32 + rg * 16;
    float4 s = {0.f, 0.f, 0.f, 0.f};
#pragma unroll 4
    for (int i = 0; i < 16; ++i) {
        size_t off = ((size_t)(b * NN + row0 + i) * DD) + cg * 4;
        float4 v = *(const float4*)(x + off);
        s.x += v.x; s.y += v.y; s.z += v.z; s.w += v.w;
        us4 o; o[0] = f2b(v.x); o[1] = f2b(v.y); o[2] = f2b(v.z); o[3] = f2b(v.w);
        *(us4*)(xb + off) = o;
    }
    *(float4*)&red[rg][cg * 4] = s;
    __syncthreads();
    if (t < 128) {
        float4 aa = *(const float4*)&red[0][t * 4];
        float4 bb4 = *(const float4*)&red[1][t * 4];
        float4 o;
        o.x = aa.x + bb4.x; o.y = aa.y + bb4.y;
        o.z = aa.z + bb4.z; o.w = aa.w + bb4.w;
        *(float4*)(part + (size_t)(b * 128 + c) * DD + t * 4) = o;
    }
}

// ---------------- kernel 2: gate = involution kernel weights (swizzled LDS) ----------------
__global__ __launch_bounds__(256, 3) void kgate(
    const unsigned short* __restrict__ xb, const unsigned short* __restrict__ c1b,
    const float* __restrict__ bn_g, const float* __restrict__ bn_b,
    const float* __restrict__ bn_m, const float* __restrict__ bn_v,
    const unsigned short* __restrict__ c2b, const float* __restrict__ conv2_b,
    float* __restrict__ gate) {
    int bid = blockIdx.x;
    int b = bid & 7, mtile = bid >> 3;
    int row0 = mtile * 128;
    int t = threadIdx.x;
    int w = t >> 6, lane = t & 63, q = lane >> 4, l16 = lane & 15;
    int wr = (w & 1) * 64, wc = (w >> 1) * 64;
    int qa = (q ^ ((l16 >> 1) & 3)) * 8;        // swizzled K-quad for fragment reads

    __shared__ unsigned short As[4096], Bs[4096];   // 128x32 tiles
    __shared__ unsigned short h_s[128][136];
    __shared__ float bnS[RED], bnT[RED];

    if (t < RED) {
        float sc = bn_g[t] * rsqrtf(bn_v[t] + 1e-5f);
        bnS[t] = sc;
        bnT[t] = bn_b[t] - bn_m[t] * sc;
    }

    f4 acc[4][4];
#pragma unroll
    for (int mi = 0; mi < 4; ++mi)
#pragma unroll
        for (int ni = 0; ni < 4; ++ni) acc[mi][ni] = (f4){0.f, 0.f, 0.f, 0.f};

    const unsigned short* abase = xb + ((size_t)(b * NN + row0) * DD);
    // stage: global K-quad pre-swizzled so linear LDS write == swizzled layout
    const int r1 = t >> 2, k1 = (((t & 3) ^ ((t >> 3) & 3))) * 8;
    const int r2 = 64 + r1;
    unsigned short* As1 = &As[(size_t)w * 512];         // wave-uniform lds bases
    unsigned short* As2 = &As[2048 + (size_t)w * 512];
    unsigned short* Bs1 = &Bs[(size_t)w * 512];
    unsigned short* Bs2 = &Bs[2048 + (size_t)w * 512];

    for (int ks = 0; ks < 16; ++ks) {
        __syncthreads();
        int kk = ks * 32;
        gld16(abase + (size_t)r1 * DD + kk + k1, As1);
        gld16(abase + (size_t)r2 * DD + kk + k1, As2);
        gld16(c1b + (size_t)r1 * DD + kk + k1, Bs1);
        gld16(c1b + (size_t)r2 * DD + kk + k1, Bs2);
        __syncthreads();
        bf8 af[4], bv[4];
#pragma unroll
        for (int mi = 0; mi < 4; ++mi) af[mi] = *(const bf8*)&As[(wr + mi * 16 + l16) * 32 + qa];
#pragma unroll
        for (int ni = 0; ni < 4; ++ni) bv[ni] = *(const bf8*)&Bs[(wc + ni * 16 + l16) * 32 + qa];
#pragma unroll
        for (int ni = 0; ni < 4; ++ni)
#pragma unroll
            for (int mi = 0; mi < 4; ++mi)
                acc[mi][ni] = __builtin_amdgcn_mfma_f32_16x16x32_bf16(af[mi], bv[ni], acc[mi][ni], 0, 0, 0);
    }
    __syncthreads();
    // BN + ReLU -> h_s (bf16)
#pragma unroll
    for (int ni = 0; ni < 4; ++ni) {
        int hc = wc + ni * 16 + l16;
        float sc = bnS[hc], sh = bnT[hc];
#pragma unroll
        for (int mi = 0; mi < 4; ++mi)
#pragma unroll
            for (int r = 0; r < 4; ++r) {
                int row = wr + mi * 16 + q * 4 + r;
                h_s[row][hc] = f2b(fmaxf(acc[mi][ni][r] * sc + sh, 0.f));
            }
    }
    __syncthreads();
    // Phase 2: gate = h @ c2b^T + bias. wave w: rows w*32..w*32+31, 2x2 tiles
    f4 a2[2][2];
#pragma unroll
    for (int mi = 0; mi < 2; ++mi)
#pragma unroll
        for (int ni = 0; ni < 2; ++ni) a2[mi][ni] = (f4){0.f, 0.f, 0.f, 0.f};
#pragma unroll
    for (int ks = 0; ks < 4; ++ks) {
        bf8 ah[2], bh[2];
#pragma unroll
        for (int mi = 0; mi < 2; ++mi)
            ah[mi] = *(const bf8*)&h_s[w * 32 + mi * 16 + l16][ks * 32 + q * 8];
#pragma unroll
        for (int ni = 0; ni < 2; ++ni)
            bh[ni] = *(const bf8*)(c2b + (ni * 16 + l16) * RED + ks * 32 + q * 8);
#pragma unroll
        for (int ni = 0; ni < 2; ++ni)
#pragma unroll
            for (int mi = 0; mi < 2; ++mi)
                a2[mi][ni] = __builtin_amdgcn_mfma_f32_16x16x32_bf16(ah[mi], bh[ni], a2[mi][ni], 0, 0, 0);
    }
#pragma unroll
    for (int ni = 0; ni < 2; ++ni) {
        int g = ni * 16 + l16;
        float cb = conv2_b[g];
#pragma unroll
        for (int mi = 0; mi < 2; ++mi)
#pragma unroll
            for (int r = 0; r < 4; ++r) {
                int row = w * 32 + mi * 16 + q * 4 + r;
                gate[((size_t)(b * NN + row0 + row)) * GG + g] = a2[mi][ni][r] + cb;
            }
    }
}

// ---------------- kernel 3: attention MLP + softmax + bb (parallelized) ----------------
__global__ __launch_bounds__(256) void katt(const float* __restrict__ part,
                                            const float* __restrict__ fc1_w,
                                            const float* __restrict__ fc2_w,
                                            const float* __restrict__ fc2_b,
                                            const float* __restrict__ dyn_b,
                                            float* __restrict__ att, float* __restrict__ bb) {
    int b = blockIdx.x, t = threadIdx.x;
    __shared__ float sh[2][512];
    __shared__ float pooled[512];
    __shared__ float a_s[HID + 3];
    __shared__ float att_s[4];
    {
        int cg = t & 127, half = t >> 7;
        const float* pb = part + ((size_t)b * 128 + half * 64) * DD + cg * 4;
        float4 s = {0.f, 0.f, 0.f, 0.f};
#pragma unroll 8
        for (int r = 0; r < 64; ++r) {
            float4 v = *(const float4*)(pb + (size_t)r * DD);
            s.x += v.x; s.y += v.y; s.z += v.z; s.w += v.w;
        }
        *(float4*)&sh[half][cg * 4] = s;
    }
    __syncthreads();
    if (t < 128) {
        float4 aa = *(const float4*)&sh[0][t * 4];
        float4 bb4 = *(const float4*)&sh[1][t * 4];
        float4 o;
        o.x = (aa.x + bb4.x) * (1.0f / (float)NN);
        o.y = (aa.y + bb4.y) * (1.0f / (float)NN);
        o.z = (aa.z + bb4.z) * (1.0f / (float)NN);
        o.w = (aa.w + bb4.w) * (1.0f / (float)NN);
        *(float4*)&pooled[t * 4] = o;
    }
    __syncthreads();
    int wv = t >> 6, ln = t & 63;
    float pl[8];
    {
        float4 p0 = *(const float4*)&pooled[ln * 8];
        float4 p1 = *(const float4*)&pooled[ln * 8 + 4];
        pl[0] = p0.x; pl[1] = p0.y; pl[2] = p0.z; pl[3] = p0.w;
        pl[4] = p1.x; pl[5] = p1.y; pl[6] = p1.z; pl[7] = p1.w;
    }
    for (int jb = wv * 4; jb < 128; jb += 16) {
        float s4[4];
#pragma unroll
        for (int u = 0; u < 4; ++u) {
            const float* wr = fc1_w + (size_t)(jb + u) * DD + ln * 8;
            float4 w0 = *(const float4*)wr;
            float4 w1 = *(const float4*)(wr + 4);
            s4[u] = w0.x * pl[0] + w0.y * pl[1] + w0.z * pl[2] + w0.w * pl[3] +
                    w1.x * pl[4] + w1.y * pl[5] + w1.z * pl[6] + w1.w * pl[7];
        }
#pragma unroll
        for (int u = 0; u < 4; ++u) {
            float v = s4[u];
#pragma unroll
            for (int off = 32; off >= 1; off >>= 1) v += __shfl_xor(v, off);
            if (ln == 0) a_s[jb + u] = fmaxf(v, 0.f);
        }
    }
    if (wv == 0) {      // tail j = 128
        const float* wr = fc1_w + (size_t)128 * DD + ln * 8;
        float4 w0 = *(const float4*)wr;
        float4 w1 = *(const float4*)(wr + 4);
        float v = w0.x * pl[0] + w0.y * pl[1] + w0.z * pl[2] + w0.w * pl[3] +
                  w1.x * pl[4] + w1.y * pl[5] + w1.z * pl[6] + w1.w * pl[7];
#pragma unroll
        for (int off = 32; off >= 1; off >>= 1) v += __shfl_xor(v, off);
        if (ln == 0) a_s[128] = fmaxf(v, 0.f);
    }
    __syncthreads();
    {
        float v = 0.f;
        for (int j = ln; j < HID; j += 64) v += a_s[j] * fc2_w[wv * HID + j];
#pragma unroll
        for (int off = 32; off >= 1; off >>= 1) v += __shfl_xor(v, off);
        if (ln == 0) att_s[wv] = (v + fc2_b[wv]) * (1.0f / 34.0f);
    }
    __syncthreads();
    if (t == 0) {
        float lg[4], mx = -1e30f;
#pragma unroll
        for (int k = 0; k < 4; ++k) { lg[k] = att_s[k]; mx = fmaxf(mx, lg[k]); }
        float den = 0.f;
#pragma unroll
        for (int k = 0; k < 4; ++k) { lg[k] = __expf(lg[k] - mx); den += lg[k]; }
#pragma unroll
        for (int k = 0; k < 4; ++k) {
            float a = lg[k] / den;
            att_s[k] = a; att[b * 4 + k] = a;
        }
    }
    __syncthreads();
    float a0 = att_s[0], a1 = att_s[1], a2 = att_s[2], a3 = att_s[3];
    for (int o = t; o < DD; o += 256) {
        bb[b * DD + o] = a0 * dyn_b[o] + a1 * dyn_b[DD + o] +
                         a2 * dyn_b[2 * DD + o] + a3 * dyn_b[3 * DD + o];
    }
}

// ---------------- kernel 4: Wb[b,o,d] = sum_k att[b,k]*dyn_w[k,o,d] ----------------
__global__ __launch_bounds__(256) void kwb(const float* __restrict__ dyn_w,
                                           const float* __restrict__ att,
                                           unsigned short* __restrict__ Wb) {
    int g = blockIdx.x * 256 + threadIdx.x;
    size_t pos = (size_t)g * 4;
    float4 w0 = *(const float4*)(dyn_w + pos);
    float4 w1 = *(const float4*)(dyn_w + 262144 + pos);
    float4 w2 = *(const float4*)(dyn_w + 524288 + pos);
    float4 w3 = *(const float4*)(dyn_w + 786432 + pos);
#pragma unroll
    for (int b = 0; b < 8; ++b) {
        float a0 = att[b * 4 + 0], a1 = att[b * 4 + 1], a2 = att[b * 4 + 2], a3 = att[b * 4 + 3];
        us4 o;
        o[0] = f2b(a0 * w0.x + a1 * w1.x + a2 * w2.x + a3 * w3.x);
        o[1] = f2b(a0 * w0.y + a1 * w1.y + a2 * w2.y + a3 * w3.y);
        o[2] = f2b(a0 * w0.z + a1 * w1.z + a2 * w2.z + a3 * w3.z);
        o[3] = f2b(a0 * w0.w + a1 * w1.w + a2 * w2.w + a3 * w3.w);
        *(us4*)(Wb + (size_t)b * 262144 + pos) = o;
    }
}

// ---------------- kernel 5 (fused GEMM + gate-residual + LayerNorm + residual) ----------------
// BM=64, BN=512, BK=32, 512 threads / 8 waves. Double-buffered, swizzled LDS (2-way max).
// LDS 78336 B -> 2 blocks/CU. Epilogue: gate/x staged into aliased LDS after K-loop.
#define STG_BUF 36864                    // As(4096B) + Bs(32768B) per buffer
#define XSTR 520                         // padded x-tile stride (elems): 1040B, 16B-aligned
#define GSTR 36                          // padded gate stride (floats)
__global__ __launch_bounds__(512, 4) void kfuse(
    const unsigned short* __restrict__ xb, const unsigned short* __restrict__ Wb,
    const float* __restrict__ bb, const float* __restrict__ gate,
    const float* __restrict__ lnG, const float* __restrict__ lnB,
    float* __restrict__ out) {
    int bid = blockIdx.x;
    int b = bid & 7, mtile = bid >> 3;          // same-b blocks stride-8 -> L2 keeps Wb[b]
    int row0 = mtile * 64;
    int t = threadIdx.x;
    int w = t >> 6, lane = t & 63, q = lane >> 4, l16 = lane & 15;
    int wrow = (w >> 2) * 32, wcol = (w & 3) * 128;
    int qa = (q ^ ((l16 >> 1) & 3)) * 8;        // swizzled K-quad for fragment reads

    __shared__ __align__(16) char smem[78336];
    // K-loop:   [0, 73728) = 2 stage buffers {As 64x32, Bs 512x32}
    // epilogue: [0, 66560) = xs 64 x XSTR bf16 ; [66560, 75776) = gateS 64 x GSTR f32
    unsigned short* xs = (unsigned short*)smem;
    float* gateS = (float*)(smem + 66560);
    float2* redS = (float2*)(smem + 75776);           // [64][4] (s,sq)  (2048 B)
    float2* murs = (float2*)(smem + 77824);           // [64] (mu, rs)   (512 B)

    const unsigned short* abase = xb + ((size_t)(b * NN + row0) * DD);
    const unsigned short* wbase = Wb + ((size_t)b * DD) * DD;

    // stage addressing: global K-quad pre-swizzled, LDS write linear
    const int srow = lane >> 2, skoff = (((lane & 3) ^ ((lane >> 3) & 3))) * 8;

#define STAGE(bf, kk) do {                                                                  \
        unsigned short* Ab = (unsigned short*)(smem + (bf) * STG_BUF);                      \
        unsigned short* Bb = (unsigned short*)(smem + (bf) * STG_BUF + 4096);               \
        if (w < 4)                                                                          \
            gld16(abase + (size_t)(w * 16 + srow) * DD + (kk) + skoff, Ab + w * 512);       \
        _Pragma("unroll")                                                                   \
        for (int i_ = 0; i_ < 4; ++i_)                                                      \
            gld16(wbase + (size_t)((w * 4 + i_) * 16 + srow) * DD + (kk) + skoff,           \
                  Bb + (w * 4 + i_) * 512);                                                 \
    } while (0)

    f4 acc[2][8];
#pragma unroll
    for (int mi = 0; mi < 2; ++mi)
#pragma unroll
        for (int ni = 0; ni < 8; ++ni) acc[mi][ni] = (f4){0.f, 0.f, 0.f, 0.f};

    STAGE(0, 0);
    __syncthreads();
    for (int ks = 0; ks < 16; ++ks) {
        if (ks < 15) STAGE((ks + 1) & 1, (ks + 1) * 32);
        const unsigned short* A = (const unsigned short*)(smem + (ks & 1) * STG_BUF);
        const unsigned short* B = (const unsigned short*)(smem + (ks & 1) * STG_BUF + 4096);
        bf8 af[2], bv[8];
#pragma unroll
        for (int mi = 0; mi < 2; ++mi) af[mi] = *(const bf8*)&A[(wrow + mi * 16 + l16) * 32 + qa];
#pragma unroll
        for (int ni = 0; ni < 8; ++ni) bv[ni] = *(const bf8*)&B[(wcol + ni * 16 + l16) * 32 + qa];
#pragma unroll
        for (int ni = 0; ni < 8; ++ni)
#pragma unroll
            for (int mi = 0; mi < 2; ++mi)
                acc[mi][ni] = __builtin_amdgcn_mfma_f32_16x16x32_bf16(af[mi], bv[ni], acc[mi][ni], 0, 0, 0);
        __syncthreads();   // drains this step's stage (issued before compute -> overlapped)
    }

    // ---- epilogue ----
    // stage x rows (64 x 512, padded stride) into LDS, aliasing the stage buffers
#pragma unroll
    for (int i = 0; i < 8; ++i) {
        int row = w * 8 + i;
        gld16(abase + (size_t)row * DD + lane * 8, xs + (size_t)row * XSTR);
    }
    // gate tile -> LDS (after final K-step reads; region overlaps stage buf 1 tail)
    {
        int grow = t >> 3, gcol = (t & 7) * 4;
        *(float4*)&gateS[grow * GSTR + gcol] =
            *(const float4*)(gate + ((size_t)(b * NN + row0 + grow)) * GG + gcol);
    }
    // per-lane constants
    float bbv[8], lgv[8], lbv[8];
#pragma unroll
    for (int ni = 0; ni < 8; ++ni) {
        int col = wcol + ni * 16 + l16;
        bbv[ni] = bb[b * DD + col];
        lgv[ni] = lnG[col];
        lbv[ni] = lnB[col];
    }
    __syncthreads();   // xs + gateS ready

    int g0 = wcol >> 4;
    // pass 1: y = acc + bb + x*gate; accumulate per-row (s, sq); butterfly over l16
#pragma unroll
    for (int mi = 0; mi < 2; ++mi) {
#pragma unroll
        for (int r = 0; r < 4; ++r) {
            int row = wrow + mi * 16 + q * 4 + r;
            float4 ga = *(const float4*)&gateS[row * GSTR + g0];
            float4 gb = *(const float4*)&gateS[row * GSTR + g0 + 4];
            float gv[8] = {ga.x, ga.y, ga.z, ga.w, gb.x, gb.y, gb.z, gb.w};
            float s = 0.f, sq = 0.f;
#pragma unroll
            for (int ni = 0; ni < 8; ++ni) {
                int col = wcol + ni * 16 + l16;
                float xv = b2f(xs[(size_t)row * XSTR + col]);
                float y = acc[mi][ni][r] + bbv[ni] + xv * gv[ni];
                acc[mi][ni][r] = y;
                s += y; sq += y * y;
            }
#pragma unroll
            for (int off = 8; off >= 1; off >>= 1) {
                s += __shfl_xor(s, off);
                sq += __shfl_xor(sq, off);
            }
            if (l16 == 0) redS[row * 4 + (w & 3)] = make_float2(s, sq);
        }
    }
    __syncthreads();
    if (t < 64) {
        float2 r0 = redS[t * 4], r1 = redS[t * 4 + 1], r2 = redS[t * 4 + 2], r3 = redS[t * 4 + 3];
        float s = r0.x + r1.x + r2.x + r3.x;
        float sq = r0.y + r1.y + r2.y + r3.y;
        float mu = s * (1.f / 512.f);
        float rs = rsqrtf(sq * (1.f / 512.f) - mu * mu + 1e-5f);
        murs[t] = make_float2(mu, rs);
    }
    __syncthreads();
    // pass 2: normalize + residual, store
#pragma unroll
    for (int mi = 0; mi < 2; ++mi) {
#pragma unroll
        for (int r = 0; r < 4; ++r) {
            int row = wrow + mi * 16 + q * 4 + r;
            float2 mr = murs[row];
            float* op = out + ((size_t)(b * NN + row0 + row)) * DD;
#pragma unroll
            for (int ni = 0; ni < 8; ++ni) {
                int col = wcol + ni * 16 + l16;
                float xv = b2f(xs[(size_t)row * XSTR + col]);
                op[col] = (acc[mi][ni][r] - mr.x) * mr.y * lgv[ni] + lbv[ni] + xv;
            }
        }
    }
#undef STAGE
}

extern "C" void kernel_launch(void* const* d_in, const int* in_sizes, int n_in,
                              void* d_out, int out_size, void* d_ws, size_t ws_size,
                              hipStream_t stream) {
    const float* x       = (const float*)d_in[0];
    const float* conv1_w = (const float*)d_in[1];
    const float* bn_g    = (const float*)d_in[2];
    const float* bn_b    = (const float*)d_in[3];
    const float* bn_m    = (const float*)d_in[4];
    const float* bn_v    = (const float*)d_in[5];
    const float* conv2_w = (const float*)d_in[6];
    const float* conv2_b = (const float*)d_in[7];
    const float* fc1_w   = (const float*)d_in[8];
    const float* fc2_w   = (const float*)d_in[9];
    const float* fc2_b   = (const float*)d_in[10];
    const float* dyn_w   = (const float*)d_in[11];
    const float* dyn_b   = (const float*)d_in[12];
    const float* lnG     = (const float*)d_in[13];
    const float* lnB     = (const float*)d_in[14];
    float* out = (float*)d_out;

    char* ws = (char*)d_ws;
    unsigned short* xb   = (unsigned short*)ws;                // 33554432
    float* part          = (float*)(ws + 33554432);            // 2097152 (region sized 4 MB)
    float* att           = (float*)(ws + 37748736);            // 128
    float* bbw           = (float*)(ws + 37748864);            // 16384
    unsigned short* c1b  = (unsigned short*)(ws + 37765248);   // 131072
    unsigned short* c2b  = (unsigned short*)(ws + 37896320);   // 8192
    float* gate          = (float*)(ws + 37904512);            // 4194304
    unsigned short* Wb   = (unsigned short*)(ws + 42098816);   // 4194304  (total ~46.3 MB)

    kpre<<<dim3(137, 8), 256, 0, stream>>>(x, conv1_w, conv2_w, part, xb, c1b, c2b);
    kgate<<<256, 256, 0, stream>>>(xb, c1b, bn_g, bn_b, bn_m, bn_v, c2b, conv2_b, gate);
    katt<<<8, 256, 0, stream>>>(part, fc1_w, fc2_w, fc2_b, dyn_b, att, bbw);
    kwb<<<256, 256, 0, stream>>>(dyn_w, att, Wb);
    kfuse<<<512, 512, 0, stream>>>(xb, Wb, bbw, gate, lnG, lnB, out);
}

// Round 4
// 211.988 us; speedup vs baseline: 1.1320x; 1.1320x over previous
//
#include <hip/hip_runtime.h>

#define DI __device__ __forceinline__

typedef __bf16 bf8 __attribute__((ext_vector_type(8)));
typedef float f4 __attribute__((ext_vector_type(4)));
typedef unsigned short us4 __attribute__((ext_vector_type(4)));
typedef unsigned short us8 __attribute__((ext_vector_type(8)));

// dims
#define BB 8
#define NN 4096
#define DD 512
#define RED 128
#define GG 32
#define HID 129

DI float b2f(unsigned short u) {
    union { unsigned int i; float f; } c; c.i = ((unsigned int)u) << 16; return c.f;
}
DI unsigned short f2b(float f) {
    union { float f; unsigned int i; } c; c.f = f;
    unsigned int u = c.i;
    return (unsigned short)((u + 0x7fffu + ((u >> 16) & 1u)) >> 16);
}

typedef const __attribute__((address_space(1))) void* gp1_t;
typedef __attribute__((address_space(3))) void* lp3_t;
// async global->LDS DMA, 16B per lane; lds base must be wave-uniform, HW adds lane*16
DI void gld16(const void* g, void* l) {
    __builtin_amdgcn_global_load_lds((gp1_t)g, (lp3_t)l, 16, 0, 0);
}

// ---------------- kernel 1: x -> bf16 + pooled partial sums (fully block-reduced), kcvt merged ----------------
__global__ __launch_bounds__(256) void kpre(const float* __restrict__ x,
                                            const float* __restrict__ conv1_w,
                                            const float* __restrict__ conv2_w,
                                            float* __restrict__ part,
                                            unsigned short* __restrict__ xb,
                                            unsigned short* __restrict__ c1b,
                                            unsigned short* __restrict__ c2b) {
    int c = blockIdx.x, b = blockIdx.y, t = threadIdx.x;
    __shared__ float red[2][512];
    if (c >= 128) {
        int idx = ((c - 128) * 8 + b) * 256 + t;    // 0..18431, need 17408
        if (idx < 16384) {
            size_t off = (size_t)idx * 4;
            float4 v = *(const float4*)(conv1_w + off);
            us4 o; o[0] = f2b(v.x); o[1] = f2b(v.y); o[2] = f2b(v.z); o[3] = f2b(v.w);
            *(us4*)(c1b + off) = o;
        } else if (idx < 17408) {
            size_t off = (size_t)(idx - 16384) * 4;
            float4 v = *(const float4*)(conv2_w + off);
            us4 o; o[0] = f2b(v.x); o[1] = f2b(v.y); o[2] = f2b(v.z); o[3] = f2b(v.w);
            *(us4*)(c2b + off) = o;
        }
        return;
    }
    int rg = t >> 7, cg = t & 127;
    int row0 = c * 32 + rg * 16;
    float4 s = {0.f, 0.f, 0.f, 0.f};
#pragma unroll 4
    for (int i = 0; i < 16; ++i) {
        size_t off = ((size_t)(b * NN + row0 + i) * DD) + cg * 4;
        float4 v = *(const float4*)(x + off);
        s.x += v.x; s.y += v.y; s.z += v.z; s.w += v.w;
        us4 o; o[0] = f2b(v.x); o[1] = f2b(v.y); o[2] = f2b(v.z); o[3] = f2b(v.w);
        *(us4*)(xb + off) = o;
    }
    *(float4*)&red[rg][cg * 4] = s;
    __syncthreads();
    if (t < 128) {
        float4 aa = *(const float4*)&red[0][t * 4];
        float4 bb4 = *(const float4*)&red[1][t * 4];
        float4 o;
        o.x = aa.x + bb4.x; o.y = aa.y + bb4.y;
        o.z = aa.z + bb4.z; o.w = aa.w + bb4.w;
        *(float4*)(part + (size_t)(b * 128 + c) * DD + t * 4) = o;
    }
}

// ---------------- kernel 2: gate = involution kernel weights (swizzled LDS) ----------------
__global__ __launch_bounds__(256, 3) void kgate(
    const unsigned short* __restrict__ xb, const unsigned short* __restrict__ c1b,
    const float* __restrict__ bn_g, const float* __restrict__ bn_b,
    const float* __restrict__ bn_m, const float* __restrict__ bn_v,
    const unsigned short* __restrict__ c2b, const float* __restrict__ conv2_b,
    float* __restrict__ gate) {
    int bid = blockIdx.x;
    int b = bid & 7, mtile = bid >> 3;
    int row0 = mtile * 128;
    int t = threadIdx.x;
    int w = t >> 6, lane = t & 63, q = lane >> 4, l16 = lane & 15;
    int wr = (w & 1) * 64, wc = (w >> 1) * 64;
    int qa = (q ^ ((l16 >> 1) & 3)) * 8;        // swizzled K-quad for fragment reads

    __shared__ unsigned short As[4096], Bs[4096];   // 128x32 tiles
    __shared__ unsigned short h_s[128][136];
    __shared__ float bnS[RED], bnT[RED];

    if (t < RED) {
        float sc = bn_g[t] * rsqrtf(bn_v[t] + 1e-5f);
        bnS[t] = sc;
        bnT[t] = bn_b[t] - bn_m[t] * sc;
    }

    f4 acc[4][4];
#pragma unroll
    for (int mi = 0; mi < 4; ++mi)
#pragma unroll
        for (int ni = 0; ni < 4; ++ni) acc[mi][ni] = (f4){0.f, 0.f, 0.f, 0.f};

    const unsigned short* abase = xb + ((size_t)(b * NN + row0) * DD);
    // stage: global K-quad pre-swizzled so linear LDS write == swizzled layout
    const int r1 = t >> 2, k1 = (((t & 3) ^ ((t >> 3) & 3))) * 8;
    const int r2 = 64 + r1;
    unsigned short* As1 = &As[(size_t)w * 512];         // wave-uniform lds bases
    unsigned short* As2 = &As[2048 + (size_t)w * 512];
    unsigned short* Bs1 = &Bs[(size_t)w * 512];
    unsigned short* Bs2 = &Bs[2048 + (size_t)w * 512];

    for (int ks = 0; ks < 16; ++ks) {
        __syncthreads();
        int kk = ks * 32;
        gld16(abase + (size_t)r1 * DD + kk + k1, As1);
        gld16(abase + (size_t)r2 * DD + kk + k1, As2);
        gld16(c1b + (size_t)r1 * DD + kk + k1, Bs1);
        gld16(c1b + (size_t)r2 * DD + kk + k1, Bs2);
        __syncthreads();
        bf8 af[4], bv[4];
#pragma unroll
        for (int mi = 0; mi < 4; ++mi) af[mi] = *(const bf8*)&As[(wr + mi * 16 + l16) * 32 + qa];
#pragma unroll
        for (int ni = 0; ni < 4; ++ni) bv[ni] = *(const bf8*)&Bs[(wc + ni * 16 + l16) * 32 + qa];
#pragma unroll
        for (int ni = 0; ni < 4; ++ni)
#pragma unroll
            for (int mi = 0; mi < 4; ++mi)
                acc[mi][ni] = __builtin_amdgcn_mfma_f32_16x16x32_bf16(af[mi], bv[ni], acc[mi][ni], 0, 0, 0);
    }
    __syncthreads();
    // BN + ReLU -> h_s (bf16)
#pragma unroll
    for (int ni = 0; ni < 4; ++ni) {
        int hc = wc + ni * 16 + l16;
        float sc = bnS[hc], sh = bnT[hc];
#pragma unroll
        for (int mi = 0; mi < 4; ++mi)
#pragma unroll
            for (int r = 0; r < 4; ++r) {
                int row = wr + mi * 16 + q * 4 + r;
                h_s[row][hc] = f2b(fmaxf(acc[mi][ni][r] * sc + sh, 0.f));
            }
    }
    __syncthreads();
    // Phase 2: gate = h @ c2b^T + bias. wave w: rows w*32..w*32+31, 2x2 tiles
    f4 a2[2][2];
#pragma unroll
    for (int mi = 0; mi < 2; ++mi)
#pragma unroll
        for (int ni = 0; ni < 2; ++ni) a2[mi][ni] = (f4){0.f, 0.f, 0.f, 0.f};
#pragma unroll
    for (int ks = 0; ks < 4; ++ks) {
        bf8 ah[2], bh[2];
#pragma unroll
        for (int mi = 0; mi < 2; ++mi)
            ah[mi] = *(const bf8*)&h_s[w * 32 + mi * 16 + l16][ks * 32 + q * 8];
#pragma unroll
        for (int ni = 0; ni < 2; ++ni)
            bh[ni] = *(const bf8*)(c2b + (ni * 16 + l16) * RED + ks * 32 + q * 8);
#pragma unroll
        for (int ni = 0; ni < 2; ++ni)
#pragma unroll
            for (int mi = 0; mi < 2; ++mi)
                a2[mi][ni] = __builtin_amdgcn_mfma_f32_16x16x32_bf16(ah[mi], bh[ni], a2[mi][ni], 0, 0, 0);
    }
#pragma unroll
    for (int ni = 0; ni < 2; ++ni) {
        int g = ni * 16 + l16;
        float cb = conv2_b[g];
#pragma unroll
        for (int mi = 0; mi < 2; ++mi)
#pragma unroll
            for (int r = 0; r < 4; ++r) {
                int row = w * 32 + mi * 16 + q * 4 + r;
                gate[((size_t)(b * NN + row0 + row)) * GG + g] = a2[mi][ni][r] + cb;
            }
    }
}

// ---------------- kernel 3: attention MLP + softmax + bb (parallelized) ----------------
__global__ __launch_bounds__(256) void katt(const float* __restrict__ part,
                                            const float* __restrict__ fc1_w,
                                            const float* __restrict__ fc2_w,
                                            const float* __restrict__ fc2_b,
                                            const float* __restrict__ dyn_b,
                                            float* __restrict__ att, float* __restrict__ bb) {
    int b = blockIdx.x, t = threadIdx.x;
    __shared__ float sh[2][512];
    __shared__ float pooled[512];
    __shared__ float a_s[HID + 3];
    __shared__ float att_s[4];
    {
        int cg = t & 127, half = t >> 7;
        const float* pb = part + ((size_t)b * 128 + half * 64) * DD + cg * 4;
        float4 s = {0.f, 0.f, 0.f, 0.f};
#pragma unroll 8
        for (int r = 0; r < 64; ++r) {
            float4 v = *(const float4*)(pb + (size_t)r * DD);
            s.x += v.x; s.y += v.y; s.z += v.z; s.w += v.w;
        }
        *(float4*)&sh[half][cg * 4] = s;
    }
    __syncthreads();
    if (t < 128) {
        float4 aa = *(const float4*)&sh[0][t * 4];
        float4 bb4 = *(const float4*)&sh[1][t * 4];
        float4 o;
        o.x = (aa.x + bb4.x) * (1.0f / (float)NN);
        o.y = (aa.y + bb4.y) * (1.0f / (float)NN);
        o.z = (aa.z + bb4.z) * (1.0f / (float)NN);
        o.w = (aa.w + bb4.w) * (1.0f / (float)NN);
        *(float4*)&pooled[t * 4] = o;
    }
    __syncthreads();
    int wv = t >> 6, ln = t & 63;
    float pl[8];
    {
        float4 p0 = *(const float4*)&pooled[ln * 8];
        float4 p1 = *(const float4*)&pooled[ln * 8 + 4];
        pl[0] = p0.x; pl[1] = p0.y; pl[2] = p0.z; pl[3] = p0.w;
        pl[4] = p1.x; pl[5] = p1.y; pl[6] = p1.z; pl[7] = p1.w;
    }
    for (int jb = wv * 4; jb < 128; jb += 16) {
        float s4[4];
#pragma unroll
        for (int u = 0; u < 4; ++u) {
            const float* wr = fc1_w + (size_t)(jb + u) * DD + ln * 8;
            float4 w0 = *(const float4*)wr;
            float4 w1 = *(const float4*)(wr + 4);
            s4[u] = w0.x * pl[0] + w0.y * pl[1] + w0.z * pl[2] + w0.w * pl[3] +
                    w1.x * pl[4] + w1.y * pl[5] + w1.z * pl[6] + w1.w * pl[7];
        }
#pragma unroll
        for (int u = 0; u < 4; ++u) {
            float v = s4[u];
#pragma unroll
            for (int off = 32; off >= 1; off >>= 1) v += __shfl_xor(v, off);
            if (ln == 0) a_s[jb + u] = fmaxf(v, 0.f);
        }
    }
    if (wv == 0) {      // tail j = 128
        const float* wr = fc1_w + (size_t)128 * DD + ln * 8;
        float4 w0 = *(const float4*)wr;
        float4 w1 = *(const float4*)(wr + 4);
        float v = w0.x * pl[0] + w0.y * pl[1] + w0.z * pl[2] + w0.w * pl[3] +
                  w1.x * pl[4] + w1.y * pl[5] + w1.z * pl[6] + w1.w * pl[7];
#pragma unroll
        for (int off = 32; off >= 1; off >>= 1) v += __shfl_xor(v, off);
        if (ln == 0) a_s[128] = fmaxf(v, 0.f);
    }
    __syncthreads();
    {
        float v = 0.f;
        for (int j = ln; j < HID; j += 64) v += a_s[j] * fc2_w[wv * HID + j];
#pragma unroll
        for (int off = 32; off >= 1; off >>= 1) v += __shfl_xor(v, off);
        if (ln == 0) att_s[wv] = (v + fc2_b[wv]) * (1.0f / 34.0f);
    }
    __syncthreads();
    if (t == 0) {
        float lg[4], mx = -1e30f;
#pragma unroll
        for (int k = 0; k < 4; ++k) { lg[k] = att_s[k]; mx = fmaxf(mx, lg[k]); }
        float den = 0.f;
#pragma unroll
        for (int k = 0; k < 4; ++k) { lg[k] = __expf(lg[k] - mx); den += lg[k]; }
#pragma unroll
        for (int k = 0; k < 4; ++k) {
            float a = lg[k] / den;
            att_s[k] = a; att[b * 4 + k] = a;
        }
    }
    __syncthreads();
    float a0 = att_s[0], a1 = att_s[1], a2 = att_s[2], a3 = att_s[3];
    for (int o = t; o < DD; o += 256) {
        bb[b * DD + o] = a0 * dyn_b[o] + a1 * dyn_b[DD + o] +
                         a2 * dyn_b[2 * DD + o] + a3 * dyn_b[3 * DD + o];
    }
}

// ---------------- kernel 4: Wb[b,o,d] = sum_k att[b,k]*dyn_w[k,o,d] ----------------
__global__ __launch_bounds__(256) void kwb(const float* __restrict__ dyn_w,
                                           const float* __restrict__ att,
                                           unsigned short* __restrict__ Wb) {
    int g = blockIdx.x * 256 + threadIdx.x;
    size_t pos = (size_t)g * 4;
    float4 w0 = *(const float4*)(dyn_w + pos);
    float4 w1 = *(const float4*)(dyn_w + 262144 + pos);
    float4 w2 = *(const float4*)(dyn_w + 524288 + pos);
    float4 w3 = *(const float4*)(dyn_w + 786432 + pos);
#pragma unroll
    for (int b = 0; b < 8; ++b) {
        float a0 = att[b * 4 + 0], a1 = att[b * 4 + 1], a2 = att[b * 4 + 2], a3 = att[b * 4 + 3];
        us4 o;
        o[0] = f2b(a0 * w0.x + a1 * w1.x + a2 * w2.x + a3 * w3.x);
        o[1] = f2b(a0 * w0.y + a1 * w1.y + a2 * w2.y + a3 * w3.y);
        o[2] = f2b(a0 * w0.z + a1 * w1.z + a2 * w2.z + a3 * w3.z);
        o[3] = f2b(a0 * w0.w + a1 * w1.w + a2 * w2.w + a3 * w3.w);
        *(us4*)(Wb + (size_t)b * 262144 + pos) = o;
    }
}

// ---------------- kernel 5 (fused GEMM + gate-residual + LayerNorm + residual) ----------------
// BM=64, BN=512, BK=32, 512 threads / 8 waves. Triple-buffered, depth-2 counted-vmcnt
// pipeline: one raw s_barrier per K-step; per-wave s_waitcnt vmcnt(L) (L = own loads/stage)
// so the two newest stages stay in flight across barriers. Swizzled LDS (2-way max).
// Buffer safety: window between barrier(ks) and barrier(ks+1) touches only
// STAGE(ks+2) -> buf (ks+2)%3 and frag reads(ks) -> buf ks%3 (disjoint for all ks).
#define NBUF 3
#define STG_BUF 36864                    // As(4096B) + Bs(32768B) per buffer
#define XSTR 520                         // padded x-tile stride (elems): 1040B, 16B-aligned
#define GSTR 36                          // padded gate stride (floats)
__global__ __launch_bounds__(512) void kfuse(
    const unsigned short* __restrict__ xb, const unsigned short* __restrict__ Wb,
    const float* __restrict__ bb, const float* __restrict__ gate,
    const float* __restrict__ lnG, const float* __restrict__ lnB,
    float* __restrict__ out) {
    int bid = blockIdx.x;
    int b = bid & 7, mtile = bid >> 3;          // same-b blocks stride-8 -> L2 keeps Wb[b]
    int row0 = mtile * 64;
    int t = threadIdx.x;
    int w = t >> 6, lane = t & 63, q = lane >> 4, l16 = lane & 15;
    int wrow = (w >> 2) * 32, wcol = (w & 3) * 128;
    int qa = (q ^ ((l16 >> 1) & 3)) * 8;        // swizzled K-quad for fragment reads

    __shared__ __align__(16) char smem[110592];   // 3 stage buffers; epilogue aliases
    unsigned short* xs = (unsigned short*)smem;               // 64 x XSTR bf16 (66560 B)
    float* gateS = (float*)(smem + 66560);                    // 64 x GSTR f32  (9216 B)
    float2* redS = (float2*)(smem + 75776);                   // [64][4] (s,sq) (2048 B)
    float2* murs = (float2*)(smem + 77824);                   // [64] (mu, rs)  (512 B)

    const unsigned short* abase = xb + ((size_t)(b * NN + row0) * DD);
    const unsigned short* wbase = Wb + ((size_t)b * DD) * DD;

    // stage addressing: global K-quad pre-swizzled, LDS write linear
    const int srow = lane >> 2, skoff = (((lane & 3) ^ ((lane >> 3) & 3))) * 8;

#define STAGE(bf, kk) do {                                                                  \
        unsigned short* Ab = (unsigned short*)(smem + (bf) * STG_BUF);                      \
        unsigned short* Bb = (unsigned short*)(smem + (bf) * STG_BUF + 4096);               \
        if (w < 4)                                                                          \
            gld16(abase + (size_t)(w * 16 + srow) * DD + (kk) + skoff, Ab + w * 512);       \
        _Pragma("unroll")                                                                   \
        for (int i_ = 0; i_ < 4; ++i_)                                                      \
            gld16(wbase + (size_t)((w * 4 + i_) * 16 + srow) * DD + (kk) + skoff,           \
                  Bb + (w * 4 + i_) * 512);                                                 \
    } while (0)

    f4 acc[2][8];
#pragma unroll
    for (int mi = 0; mi < 2; ++mi)
#pragma unroll
        for (int ni = 0; ni < 8; ++ni) acc[mi][ni] = (f4){0.f, 0.f, 0.f, 0.f};

    STAGE(0, 0);
    STAGE(1, 32);
    for (int ks = 0; ks < 16; ++ks) {
        // drain own loads of stage ks; allow the newest stage (ks+1) to stay in flight
        if (ks < 15) {
            if (w < 4) asm volatile("s_waitcnt vmcnt(5)" ::: "memory");
            else       asm volatile("s_waitcnt vmcnt(4)" ::: "memory");
        } else {
            asm volatile("s_waitcnt vmcnt(0)" ::: "memory");
        }
        __builtin_amdgcn_s_barrier();
        __builtin_amdgcn_sched_barrier(0);
        if (ks + 2 < 16) STAGE((ks + 2) % NBUF, (ks + 2) * 32);
        const unsigned short* A = (const unsigned short*)(smem + (ks % NBUF) * STG_BUF);
        const unsigned short* B = (const unsigned short*)(smem + (ks % NBUF) * STG_BUF + 4096);
        bf8 af[2], bv[8];
#pragma unroll
        for (int mi = 0; mi < 2; ++mi) af[mi] = *(const bf8*)&A[(wrow + mi * 16 + l16) * 32 + qa];
#pragma unroll
        for (int ni = 0; ni < 8; ++ni) bv[ni] = *(const bf8*)&B[(wcol + ni * 16 + l16) * 32 + qa];
#pragma unroll
        for (int ni = 0; ni < 8; ++ni)
#pragma unroll
            for (int mi = 0; mi < 2; ++mi)
                acc[mi][ni] = __builtin_amdgcn_mfma_f32_16x16x32_bf16(af[mi], bv[ni], acc[mi][ni], 0, 0, 0);
    }
    __syncthreads();   // all frag reads done -> epilogue may overwrite stage buffers

    // ---- epilogue ----
    // stage x rows (64 x 512, padded stride) into LDS, aliasing the stage buffers
#pragma unroll
    for (int i = 0; i < 8; ++i) {
        int row = w * 8 + i;
        gld16(abase + (size_t)row * DD + lane * 8, xs + (size_t)row * XSTR);
    }
    // gate tile -> LDS
    {
        int grow = t >> 3, gcol = (t & 7) * 4;
        *(float4*)&gateS[grow * GSTR + gcol] =
            *(const float4*)(gate + ((size_t)(b * NN + row0 + grow)) * GG + gcol);
    }
    // per-lane constants
    float bbv[8], lgv[8], lbv[8];
#pragma unroll
    for (int ni = 0; ni < 8; ++ni) {
        int col = wcol + ni * 16 + l16;
        bbv[ni] = bb[b * DD + col];
        lgv[ni] = lnG[col];
        lbv[ni] = lnB[col];
    }
    __syncthreads();   // xs + gateS ready

    int g0 = wcol >> 4;
    // pass 1: y = acc + bb + x*gate; accumulate per-row (s, sq); butterfly over l16
#pragma unroll
    for (int mi = 0; mi < 2; ++mi) {
#pragma unroll
        for (int r = 0; r < 4; ++r) {
            int row = wrow + mi * 16 + q * 4 + r;
            float4 ga = *(const float4*)&gateS[row * GSTR + g0];
            float4 gb = *(const float4*)&gateS[row * GSTR + g0 + 4];
            float gv[8] = {ga.x, ga.y, ga.z, ga.w, gb.x, gb.y, gb.z, gb.w};
            float s = 0.f, sq = 0.f;
#pragma unroll
            for (int ni = 0; ni < 8; ++ni) {
                int col = wcol + ni * 16 + l16;
                float xv = b2f(xs[(size_t)row * XSTR + col]);
                float y = acc[mi][ni][r] + bbv[ni] + xv * gv[ni];
                acc[mi][ni][r] = y;
                s += y; sq += y * y;
            }
#pragma unroll
            for (int off = 8; off >= 1; off >>= 1) {
                s += __shfl_xor(s, off);
                sq += __shfl_xor(sq, off);
            }
            if (l16 == 0) redS[row * 4 + (w & 3)] = make_float2(s, sq);
        }
    }
    __syncthreads();
    if (t < 64) {
        float2 r0 = redS[t * 4], r1 = redS[t * 4 + 1], r2 = redS[t * 4 + 2], r3 = redS[t * 4 + 3];
        float s = r0.x + r1.x + r2.x + r3.x;
        float sq = r0.y + r1.y + r2.y + r3.y;
        float mu = s * (1.f / 512.f);
        float rs = rsqrtf(sq * (1.f / 512.f) - mu * mu + 1e-5f);
        murs[t] = make_float2(mu, rs);
    }
    __syncthreads();
    // pass 2: normalize + residual, store
#pragma unroll
    for (int mi = 0; mi < 2; ++mi) {
#pragma unroll
        for (int r = 0; r < 4; ++r) {
            int row = wrow + mi * 16 + q * 4 + r;
            float2 mr = murs[row];
            float* op = out + ((size_t)(b * NN + row0 + row)) * DD;
#pragma unroll
            for (int ni = 0; ni < 8; ++ni) {
                int col = wcol + ni * 16 + l16;
                float xv = b2f(xs[(size_t)row * XSTR + col]);
                op[col] = (acc[mi][ni][r] - mr.x) * mr.y * lgv[ni] + lbv[ni] + xv;
            }
        }
    }
#undef STAGE
}

extern "C" void kernel_launch(void* const* d_in, const int* in_sizes, int n_in,
                              void* d_out, int out_size, void* d_ws, size_t ws_size,
                              hipStream_t stream) {
    const float* x       = (const float*)d_in[0];
    const float* conv1_w = (const float*)d_in[1];
    const float* bn_g    = (const float*)d_in[2];
    const float* bn_b    = (const float*)d_in[3];
    const float* bn_m    = (const float*)d_in[4];
    const float* bn_v    = (const float*)d_in[5];
    const float* conv2_w = (const float*)d_in[6];
    const float* conv2_b = (const float*)d_in[7];
    const float* fc1_w   = (const float*)d_in[8];
    const float* fc2_w   = (const float*)d_in[9];
    const float* fc2_b   = (const float*)d_in[10];
    const float* dyn_w   = (const float*)d_in[11];
    const float* dyn_b   = (const float*)d_in[12];
    const float* lnG     = (const float*)d_in[13];
    const float* lnB     = (const float*)d_in[14];
    float* out = (float*)d_out;

    char* ws = (char*)d_ws;
    unsigned short* xb   = (unsigned short*)ws;                // 33554432
    float* part          = (float*)(ws + 33554432);            // 2097152 (region sized 4 MB)
    float* att           = (float*)(ws + 37748736);            // 128
    float* bbw           = (float*)(ws + 37748864);            // 16384
    unsigned short* c1b  = (unsigned short*)(ws + 37765248);   // 131072
    unsigned short* c2b  = (unsigned short*)(ws + 37896320);   // 8192
    float* gate          = (float*)(ws + 37904512);            // 4194304
    unsigned short* Wb   = (unsigned short*)(ws + 42098816);   // 4194304  (total ~46.3 MB)

    kpre<<<dim3(137, 8), 256, 0, stream>>>(x, conv1_w, conv2_w, part, xb, c1b, c2b);
    kgate<<<256, 256, 0, stream>>>(xb, c1b, bn_g, bn_b, bn_m, bn_v, c2b, conv2_b, gate);
    katt<<<8, 256, 0, stream>>>(part, fc1_w, fc2_w, fc2_b, dyn_b, att, bbw);
    kwb<<<256, 256, 0, stream>>>(dyn_w, att, Wb);
    kfuse<<<512, 512, 0, stream>>>(xb, Wb, bbw, gate, lnG, lnB, out);
}